// Round 2
// baseline (637.714 us; speedup 1.0000x reference)
//
#include <hip/hip_runtime.h>

// Problem constants (from reference setup_inputs): B=8, H=512, W=512, C=16, fp32.
#define BB 8
#define HH 512
#define WW 512
#define CC 16

// Zero-fill d_out with vector stores (d_out is poisoned 0xAA before every
// timed call). Plain kernel instead of hipMemsetAsync to keep kernel_launch
// maximally graph-capture-safe.
__global__ __launch_bounds__(256) void zero_fill_f4(float4* __restrict__ p, int n4)
{
    int i = blockIdx.x * 256 + threadIdx.x;
    if (i < n4) p[i] = make_float4(0.f, 0.f, 0.f, 0.f);
}

// One thread per (pixel, channel). A wave of 64 lanes covers 4 pixels x 16
// channels -> grad_out loads are fully coalesced (256 B/wave). Flow load is a
// float2 shared by 16 lanes (L1 broadcast). Each thread does up to 4 global
// fp32 atomicAdds (one per bilinear corner).
__global__ __launch_bounds__(256) void warp_transpose_scatter(
    const float* __restrict__ gout,
    const float* __restrict__ u,
    float* __restrict__ gx)
{
    const int gid = blockIdx.x * 256 + threadIdx.x;   // [0, B*H*W*C)
    const int c   = gid & (CC - 1);
    const int p   = gid >> 4;                          // pixel index b*H*W + y*W + x
    const int x   = p & (WW - 1);
    const int y   = (p >> 9) & (HH - 1);
    const int b   = p >> 18;

    const float2 uv = reinterpret_cast<const float2*>(u)[p];
    const float sx = (float)x + uv.x;
    const float sy = (float)y + uv.y;
    const float x0f = floorf(sx);
    const float y0f = floorf(sy);
    const float wx = sx - x0f;
    const float wy = sy - y0f;
    const int x0 = (int)x0f;
    const int y0 = (int)y0f;
    const int x1 = x0 + 1;
    const int y1 = y0 + 1;

    const float g   = gout[gid];
    const float w00 = (1.0f - wy) * (1.0f - wx) * g;
    const float w01 = (1.0f - wy) * wx * g;
    const float w10 = wy * (1.0f - wx) * g;
    const float w11 = wy * wx * g;

    // Validity: unsigned compare folds (>=0 && <N) into one check.
    const bool vx0 = (unsigned)x0 < (unsigned)WW;
    const bool vx1 = (unsigned)x1 < (unsigned)WW;
    const bool vy0 = (unsigned)y0 < (unsigned)HH;
    const bool vy1 = (unsigned)y1 < (unsigned)HH;

    const int base = b * (HH * WW);   // max index B*H*W*C = 2^29 fits in int32
    if (vy0 && vx0) atomicAdd(&gx[((base + y0 * WW + x0) << 4) + c], w00);
    if (vy0 && vx1) atomicAdd(&gx[((base + y0 * WW + x1) << 4) + c], w01);
    if (vy1 && vx0) atomicAdd(&gx[((base + y1 * WW + x0) << 4) + c], w10);
    if (vy1 && vx1) atomicAdd(&gx[((base + y1 * WW + x1) << 4) + c], w11);
}

extern "C" void kernel_launch(void* const* d_in, const int* in_sizes, int n_in,
                              void* d_out, int out_size, void* d_ws, size_t ws_size,
                              hipStream_t stream) {
    const float* gout = (const float*)d_in[0];   // grad_out [B,H,W,C]
    const float* u    = (const float*)d_in[1];   // flow     [B,H,W,2]
    // d_in[2] (x) only determines output shape; unused.
    float* gx = (float*)d_out;

    const int total = BB * HH * WW * CC;         // 33,554,432
    const int n4    = total / 4;                 // 8,388,608 float4s
    zero_fill_f4<<<(n4 + 255) / 256, 256, 0, stream>>>((float4*)gx, n4);

    const int blocks = total / 256;              // 131,072
    warp_transpose_scatter<<<blocks, 256, 0, stream>>>(gout, u, gx);
}